// Round 4
// baseline (2203.413 us; speedup 1.0000x reference)
//
#include <hip/hip_runtime.h>
#include <hip/hip_bf16.h>
#include <math.h>

#define DIN 128
#define DH 256
#define DOUT 128
#define NLAYERS 8
#define EPSLN 1e-5f

typedef __hip_bfloat16 bf16;
typedef __attribute__((ext_vector_type(8))) short short8;
typedef __attribute__((ext_vector_type(4))) short short4v;
typedef __attribute__((ext_vector_type(2))) short short2v;
typedef __attribute__((ext_vector_type(4))) float f32x4;

__device__ __forceinline__ float ldf(const void* p, size_t idx, int isbf) {
    if (isbf) return __bfloat162float(((const bf16*)p)[idx]);
    return ((const float*)p)[idx];
}
__device__ __forceinline__ short f2s(float v) {
    bf16 b = __float2bfloat16(v);
    return *reinterpret_cast<short*>(&b);
}
__device__ __forceinline__ float s2f(short s) {
    unsigned int u = ((unsigned int)(unsigned short)s) << 16;
    float f;
    __builtin_memcpy(&f, &u, 4);
    return f;
}
__device__ __forceinline__ void gl_lds16(const void* g, void* l) {
    __builtin_amdgcn_global_load_lds(
        (const __attribute__((address_space(1))) unsigned int*)g,
        (__attribute__((address_space(3))) unsigned int*)l,
        16, 0, 0);
}

// ---------------- dtype probe ----------------
__global__ void k_detect(const unsigned int* __restrict__ xw, int* __restrict__ flag) {
    __shared__ int cnt;
    if (threadIdx.x == 0) cnt = 0;
    __syncthreads();
    unsigned int w = xw[threadIdx.x];
    int e = (w >> 7) & 0xFF;
    if (e >= 112 && e <= 140) atomicAdd(&cnt, 1);
    __syncthreads();
    if (threadIdx.x == 0) *flag = (cnt >= 128) ? 1 : 0;
}

// ---------------- degree + CSR build ----------------
__global__ void k_init_cnt(int* __restrict__ cnt, int N) {
    int i = blockIdx.x * blockDim.x + threadIdx.x;
    if (i < N) cnt[i] = 0;
}
__global__ void k_count(const int* __restrict__ cols, int* __restrict__ cnt, int E) {
    int e = blockIdx.x * blockDim.x + threadIdx.x;
    if (e < E) atomicAdd(&cnt[cols[e]], 1);
}
__global__ void k_dis(const int* __restrict__ cnt, float* __restrict__ dis, int N) {
    int i = blockIdx.x * blockDim.x + threadIdx.x;
    if (i < N) dis[i] = rsqrtf(1.0f + (float)cnt[i]);
}
__global__ void k_scan1(const int* __restrict__ cnt, int* __restrict__ rowptr,
                        int* __restrict__ bsum, int N) {
    __shared__ int s[256];
    int t = threadIdx.x;
    int i = blockIdx.x * 256 + t;
    s[t] = (i < N) ? cnt[i] : 0;
    __syncthreads();
    for (int off = 1; off < 256; off <<= 1) {
        int x = (t >= off) ? s[t - off] : 0;
        __syncthreads();
        s[t] += x;
        __syncthreads();
    }
    if (i < N) rowptr[i + 1] = s[t];
    if (t == 255) bsum[blockIdx.x] = s[255];
}
__global__ void k_scan2(int* __restrict__ bsum, int nb) {
    __shared__ int s[256];
    int t = threadIdx.x;
    s[t] = (t < nb) ? bsum[t] : 0;
    __syncthreads();
    for (int off = 1; off < 256; off <<= 1) {
        int x = (t >= off) ? s[t - off] : 0;
        __syncthreads();
        s[t] += x;
        __syncthreads();
    }
    if (t < nb) bsum[t] = s[t];
}
__global__ void k_scan3(int* __restrict__ rowptr, const int* __restrict__ bsum, int N) {
    int i = blockIdx.x * 256 + threadIdx.x;
    if (i == 0) rowptr[0] = 0;
    if (i < N && blockIdx.x > 0) rowptr[i + 1] += bsum[blockIdx.x - 1];
}
__global__ void k_cursor(const int* __restrict__ rowptr, int* __restrict__ cursor, int N) {
    int i = blockIdx.x * 256 + threadIdx.x;
    if (i < N) cursor[i] = rowptr[i];
}
__global__ void k_fill(const int* __restrict__ rows, const int* __restrict__ cols,
                       int* __restrict__ cursor, int* __restrict__ csr, int E) {
    int e = blockIdx.x * blockDim.x + threadIdx.x;
    if (e < E) {
        int c = cols[e], r = rows[e];
        int pos = atomicAdd(&cursor[c], 1);
        csr[pos] = r;
    }
}

__global__ void k_zero_stats(float* __restrict__ stats) {
    int t = threadIdx.x;
    if (t < 16) stats[t] = 0.0f;
}

// ------- conv weight fold+transpose: wt[l][n][k(512)] = c1*W{1,2}[k][n] + (k==n)*c0 -------
__global__ void k_transw2(const void* __restrict__ w1, const void* __restrict__ w2,
                          const int* __restrict__ flag, short* __restrict__ wt) {
    __shared__ float tile[32][33];
    int z = blockIdx.z;
    int lay = z >> 1, m = z & 1;
    const void* src = m ? w2 : w1;
    size_t sbase = (size_t)lay * 65536;
    short* dst = wt + (size_t)lay * 131072 + (size_t)m * 256;  // row stride 512
    float bl = logf(1.0f / (float)(lay + 1) + 1.0f);
    float c0 = 0.5f * (1.0f - bl);
    float c1 = 0.5f * bl;
    int isbf = *flag;
    int tx = threadIdx.x, ty = threadIdx.y;     // (32,8)
    int n0 = blockIdx.x * 32, k0 = blockIdx.y * 32;
    #pragma unroll
    for (int i = 0; i < 4; i++) {
        int k = k0 + ty + i * 8;
        tile[ty + i * 8][tx] = ldf(src, sbase + (size_t)k * 256 + n0 + tx, isbf);
    }
    __syncthreads();
    #pragma unroll
    for (int i = 0; i < 4; i++) {
        int n = n0 + ty + i * 8;
        int k = k0 + tx;
        float v = c1 * tile[tx][ty + i * 8];
        if (k == n) v += c0;
        dst[(size_t)n * 512 + k] = f2s(v);
    }
}

// ------- generic transpose to bf16: dst[n][K] = src[k][n], src is [K, Nc] -------
__global__ void k_transw_lin(const void* __restrict__ src, const int* __restrict__ flag,
                             short* __restrict__ dst, int K, int Nc) {
    __shared__ float tile[32][33];
    int isbf = *flag;
    int tx = threadIdx.x, ty = threadIdx.y;     // (32,8)
    int n0 = blockIdx.x * 32, k0 = blockIdx.y * 32;
    #pragma unroll
    for (int i = 0; i < 4; i++) {
        int k = k0 + ty + i * 8;
        tile[ty + i * 8][tx] = ldf(src, (size_t)k * Nc + n0 + tx, isbf);
    }
    __syncthreads();
    #pragma unroll
    for (int i = 0; i < 4; i++) {
        int n = n0 + ty + i * 8;
        dst[(size_t)n * K + k0 + tx] = f2s(tile[tx][ty + i * 8]);
    }
}

// ------- x conversion to guaranteed-bf16 -------
__global__ void k_convx(const void* __restrict__ x, const int* __restrict__ flag,
                        short* __restrict__ xb, int total) {
    int i = blockIdx.x * 256 + threadIdx.x;
    if (i < total) xb[i] = f2s(ldf(x, i, *flag));
}

// ---- generic MFMA GEMM: out = relu(A @ wt^T + bias). A [M,KK] bf16, wt [BN,KK] bf16 ----
// 512 threads = 8 waves, 16 rows/wave, fragment-major LDS (conflict-free).
// Optional additional sliced output: outs[s][row][32], s = col>>5 (for XCD-sliced gather).
template<int BN, int KK, int FINAL>
__global__ __launch_bounds__(512, 4) void gemm_mfma(
    const short* __restrict__ A, const short* __restrict__ wt,
    const void* __restrict__ bias, const int* __restrict__ flag,
    void* __restrict__ outp, short* __restrict__ outs, int Nn)
{
    constexpr int NT = BN / 16;
    constexpr int BROUNDS = BN / 128;   // 256->2, 128->1
    __shared__ __align__(16) short Atile[128 * 32];
    __shared__ __align__(16) short Btile[BN * 32];
    int t = threadIdx.x;
    int w = t >> 6, lane = t & 63;
    int lr = lane & 15, quad = lane >> 4;
    int row0 = blockIdx.x * 128;
    int sf = t >> 6;           // fragment 0..7
    int srow = lane & 15;      // row within fragment
    int skq = lane >> 4;       // k-quad (8 bf16 = 16B)
    f32x4 acc[NT];
    #pragma unroll
    for (int nt = 0; nt < NT; nt++)
        #pragma unroll
        for (int j = 0; j < 4; j++) acc[nt][j] = 0.f;

    for (int kb = 0; kb < KK; kb += 32) {
        int gr = row0 + sf * 16 + srow;
        if (gr >= Nn) gr = Nn - 1;
        gl_lds16(A + (size_t)gr * KK + kb + skq * 8, Atile + (size_t)t * 8);
        #pragma unroll
        for (int r = 0; r < BROUNDS; r++) {
            int n = (sf + r * 8) * 16 + srow;
            gl_lds16(wt + (size_t)n * KK + kb + skq * 8,
                     Btile + (size_t)(t + r * 512) * 8);
        }
        __syncthreads();
        short8 a = *(const short8*)(Atile + w * 512 + lane * 8);
        #pragma unroll
        for (int nt = 0; nt < NT; nt++) {
            short8 bv = *(const short8*)(Btile + nt * 512 + lane * 8);
            acc[nt] = __builtin_amdgcn_mfma_f32_16x16x32_bf16(a, bv, acc[nt], 0, 0, 0);
        }
        __syncthreads();
    }
    const int isbf = *flag;
    #pragma unroll
    for (int nt = 0; nt < NT; nt++) {
        int gc = nt * 16 + lr;
        float bb = ldf(bias, gc, isbf);
        #pragma unroll
        for (int i = 0; i < 4; i++) {
            int gr = row0 + w * 16 + quad * 4 + i;
            if (gr < Nn) {
                float v = acc[nt][i] + bb;
                v = v > 0.f ? v : 0.f;
                size_t off = (size_t)gr * BN + gc;
                if (FINAL) {
                    if (isbf) ((bf16*)outp)[off] = __float2bfloat16(v);
                    else      ((float*)outp)[off] = v;
                } else {
                    ((bf16*)outp)[off] = __float2bfloat16(v);
                    if (outs) {
                        outs[((size_t)(gc >> 5) * (size_t)Nn + gr) * 32 + (gc & 31)] = f2s(v);
                    }
                }
            }
        }
    }
}

// -------- XCD-sliced CSR gather. Slice s = blockIdx&7 (block->XCD round-robin),
// so each XCD reads only h[:, s*32..s*32+32) (3.2MB, L2-resident).
// hsrc layout: [8][N][32] bf16. Wave = 1 node; 4 neighbor-groups x 16 lanes x 2 cols.
__global__ __launch_bounds__(256) void k_gather3(
    const int* __restrict__ rowptr, const int* __restrict__ csr,
    const float* __restrict__ dis, const short* __restrict__ hsrc,
    bf16* __restrict__ agg,
    const void* __restrict__ g, const void* __restrict__ b, size_t loff,
    const float* __restrict__ stats2, float invTotal, int useLN,
    const int* __restrict__ flag, int N)
{
    int s = blockIdx.x & 7;
    int chunk = blockIdx.x >> 3;
    int t = threadIdx.x;
    int w = t >> 6, lane = t & 63;
    int grp = lane >> 4;           // neighbor group 0..3
    int cl = (lane & 15) * 2;      // col pair within slice
    int col = s * 32 + cl;
    float cA0, cA1, cB0, cB1;
    if (useLN) {
        int isbf = *flag;
        float mu = stats2[0] * invTotal;
        float var = stats2[1] * invTotal - mu * mu;
        var = var > 0.f ? var : 0.f;
        float inv = 1.0f / (sqrtf(var) + EPSLN);
        float g0 = ldf(g, loff + col, isbf), g1 = ldf(g, loff + col + 1, isbf);
        float b0 = ldf(b, loff + col, isbf), b1 = ldf(b, loff + col + 1, isbf);
        cA0 = g0 * inv; cB0 = fmaf(-g0 * inv, mu, b0);
        cA1 = g1 * inv; cB1 = fmaf(-g1 * inv, mu, b1);
    } else {
        cA0 = cA1 = 1.0f; cB0 = cB1 = 0.0f;
    }
    const short* hs = hsrc + (size_t)s * (size_t)N * 32;
    // wave handles 8 contiguous nodes
    int node0 = chunk * 32 + w * 8;
    for (int ni = 0; ni < 8; ni++) {
        int node = node0 + ni;
        if (node >= N) break;
        float dc = dis[node];
        float a0 = 0.f, a1 = 0.f;
        if (grp == 0) {
            short2v hv = *(const short2v*)(hs + (size_t)node * 32 + cl);
            float v0 = fmaf(cA0, s2f(hv[0]), cB0); v0 = v0 > 0.f ? v0 : 0.f;
            float v1 = fmaf(cA1, s2f(hv[1]), cB1); v1 = v1 > 0.f ? v1 : 0.f;
            a0 = dc * v0; a1 = dc * v1;
        }
        int ib = rowptr[node], ie = rowptr[node + 1];
        int i = ib + grp;
        int rn = (i < ie) ? __builtin_nontemporal_load(csr + i) : 0;
        while (i < ie) {
            int r = rn;
            int i2 = i + 4;
            if (i2 < ie) rn = __builtin_nontemporal_load(csr + i2);
            float wr = dis[r];
            short2v hv = *(const short2v*)(hs + (size_t)r * 32 + cl);
            float v0 = fmaf(cA0, s2f(hv[0]), cB0); v0 = v0 > 0.f ? v0 : 0.f;
            float v1 = fmaf(cA1, s2f(hv[1]), cB1); v1 = v1 > 0.f ? v1 : 0.f;
            a0 = fmaf(wr, v0, a0);
            a1 = fmaf(wr, v1, a1);
            i = i2;
        }
        a0 += __shfl_xor(a0, 16); a0 += __shfl_xor(a0, 32);
        a1 += __shfl_xor(a1, 16); a1 += __shfl_xor(a1, 32);
        if (grp == 0) {
            short2v o;
            o[0] = f2s(dc * a0);
            o[1] = f2s(dc * a1);
            *(short2v*)((short*)agg + (size_t)node * DH + col) = o;
        }
    }
}

// ---- layer GEMM (MFMA, fragment-major LDS): h = [agg|x0] @ W' + LN sums ----
// sliced=1: write h in [8][N][32] sliced layout (consumed by k_gather3 only);
// sliced=0 (last layer): row-major (consumed by k_applyT + lin2).
__global__ __launch_bounds__(512, 4) void gemm_layer3(
    const bf16* __restrict__ agg, const bf16* __restrict__ x0,
    const short* __restrict__ wt, bf16* __restrict__ h,
    float* __restrict__ stats2, int sliced, int Nn)
{
    __shared__ __align__(16) short Atile[128 * 32];
    __shared__ __align__(16) short Btile[256 * 32];
    __shared__ float sred[16];
    int t = threadIdx.x;
    int w = t >> 6, lane = t & 63;
    int lr = lane & 15, quad = lane >> 4;
    int row0 = blockIdx.x * 128;
    int sf = t >> 6;
    int srow = lane & 15;
    int skq = lane >> 4;
    f32x4 acc[16];
    #pragma unroll
    for (int nt = 0; nt < 16; nt++)
        #pragma unroll
        for (int j = 0; j < 4; j++) acc[nt][j] = 0.f;

    for (int kb = 0; kb < 512; kb += 32) {
        const short* Asrc = (const short*)((kb < DH) ? agg : x0);
        int ka = (kb & (DH - 1)) + skq * 8;
        int gr = row0 + sf * 16 + srow;
        if (gr >= Nn) gr = Nn - 1;
        gl_lds16(Asrc + (size_t)gr * DH + ka, Atile + (size_t)t * 8);
        #pragma unroll
        for (int r = 0; r < 2; r++) {
            int n = (sf + r * 8) * 16 + srow;
            gl_lds16(wt + (size_t)n * 512 + kb + skq * 8,
                     Btile + (size_t)(t + r * 512) * 8);
        }
        __syncthreads();
        short8 a = *(const short8*)(Atile + w * 512 + lane * 8);
        #pragma unroll
        for (int nt = 0; nt < 16; nt++) {
            short8 bv = *(const short8*)(Btile + nt * 512 + lane * 8);
            acc[nt] = __builtin_amdgcn_mfma_f32_16x16x32_bf16(a, bv, acc[nt], 0, 0, 0);
        }
        __syncthreads();
    }
    short* hS = (short*)h;
    float lsum = 0.f, lsq = 0.f;
    #pragma unroll
    for (int nt = 0; nt < 16; nt++) {
        int gc = nt * 16 + lr;
        #pragma unroll
        for (int i = 0; i < 4; i++) {
            int gr = row0 + w * 16 + quad * 4 + i;
            if (gr < Nn) {
                float v = acc[nt][i];
                if (sliced) {
                    hS[((size_t)(gc >> 5) * (size_t)Nn + gr) * 32 + (gc & 31)] = f2s(v);
                } else {
                    h[(size_t)gr * DH + gc] = __float2bfloat16(v);
                }
                lsum += v;
                lsq += v * v;
            }
        }
    }
    #pragma unroll
    for (int off = 32; off > 0; off >>= 1) {
        lsum += __shfl_down(lsum, off);
        lsq  += __shfl_down(lsq, off);
    }
    if (lane == 0) { sred[w] = lsum; sred[8 + w] = lsq; }
    __syncthreads();
    if (t == 0) {
        float s0 = 0.f, s1 = 0.f;
        #pragma unroll
        for (int i = 0; i < 8; i++) { s0 += sred[i]; s1 += sred[8 + i]; }
        atomicAdd(&stats2[0], s0);
        atomicAdd(&stats2[1], s1);
    }
}

// ------- final LN+relu applied in place to h (layer-8 stats) -------
__global__ void k_applyT(
    bf16* __restrict__ h, const float* __restrict__ stats2, float invTotal,
    const void* __restrict__ g, const void* __restrict__ b, size_t loff,
    const int* __restrict__ flag, int total)
{
    int idx = blockIdx.x * 256 + threadIdx.x;
    if (idx >= total) return;
    const int isbf = *flag;
    float mu = stats2[0] * invTotal;
    float var = stats2[1] * invTotal - mu * mu;
    var = var > 0.f ? var : 0.f;
    float inv = 1.0f / (sqrtf(var) + EPSLN);
    int j = idx & (DH - 1);
    float gg = ldf(g, loff + j, isbf);
    float bb = ldf(b, loff + j, isbf);
    float v = fmaf(gg * inv, __bfloat162float(h[idx]), fmaf(-gg * inv, mu, bb));
    v = v > 0.f ? v : 0.f;
    h[idx] = __float2bfloat16(v);
}

extern "C" void kernel_launch(void* const* d_in, const int* in_sizes, int n_in,
                              void* d_out, int out_size, void* d_ws, size_t ws_size,
                              hipStream_t stream) {
    const void* x      = d_in[0];
    const int*  ei     = (const int*)d_in[1];
    const void* lin1_w = d_in[2];
    const void* lin1_b = d_in[3];
    const void* conv_w1= d_in[4];
    const void* conv_w2= d_in[5];
    const void* gam    = d_in[6];
    const void* bet    = d_in[7];
    const void* lin2_w = d_in[8];
    const void* lin2_b = d_in[9];

    const int N = in_sizes[0] / DIN;
    const int E = in_sizes[1] / 2;
    const int* rows = ei;
    const int* cols = ei + E;
    const size_t NDH = (size_t)N * DH;
    const size_t Nr = ((size_t)N + 255) / 256 * 256;

    char* p = (char*)d_ws;
    auto alloc = [&](size_t bytes) { char* q = p; p += (bytes + 255) & ~(size_t)255; return q; };
    float* dis    = (float*)alloc(Nr * 4);
    float* stats  = (float*)alloc(1024);          // 16 slots: 2 per layer
    int*   flag   = (int*)(stats + 16);
    int*   cnt    = (int*)alloc(Nr * 4);
    int*   rowptr = (int*)alloc((Nr + 256) * 4);
    int*   cursor = (int*)alloc(Nr * 4);
    int*   bsum   = (int*)alloc(1024);
    int*   csr    = (int*)alloc((size_t)E * 4);
    short* wt     = (short*)alloc((size_t)NLAYERS * 131072 * 2);  // 2 MB folded conv weights
    short* w1t    = (short*)alloc((size_t)DH * DIN * 2);          // lin1^T
    short* w2t    = (short*)alloc((size_t)DOUT * DH * 2);         // lin2^T
    short* xb     = (short*)alloc((size_t)N * DIN * 2);           // x as bf16
    bf16*  agg    = (bf16*)alloc(NDH * 2);
    bf16*  x0     = (bf16*)alloc(NDH * 2);
    short* x0s    = (short*)alloc(NDH * 2);       // x0 in sliced [8][N][32] layout
    bf16*  h      = (bf16*)alloc(NDH * 2);        // sliced for layers 0..6, row-major layer 7

    dim3 blk(256);
    int nbN = (N + 255) / 256;
    dim3 gN(nbN);
    dim3 gE((E + 255) / 256);
    dim3 gB((N + 127) / 128);
    dim3 gG((unsigned)(8 * ((N + 31) / 32)));
    dim3 gElem((unsigned)((NDH + 255) / 256));
    dim3 gTW(8, 8, 16);
    dim3 bTW(32, 8);
    dim3 blk512(512);

    k_detect<<<1, 256, 0, stream>>>((const unsigned int*)x, flag);
    k_init_cnt<<<gN, blk, 0, stream>>>(cnt, N);
    k_count<<<gE, blk, 0, stream>>>(cols, cnt, E);
    k_dis<<<gN, blk, 0, stream>>>(cnt, dis, N);
    k_scan1<<<gN, blk, 0, stream>>>(cnt, rowptr, bsum, N);
    k_scan2<<<1, 256, 0, stream>>>(bsum, nbN);
    k_scan3<<<gN, blk, 0, stream>>>(rowptr, bsum, N);
    k_cursor<<<gN, blk, 0, stream>>>(rowptr, cursor, N);
    k_fill<<<gE, blk, 0, stream>>>(rows, cols, cursor, csr, E);
    k_zero_stats<<<1, 64, 0, stream>>>(stats);
    k_transw2<<<gTW, bTW, 0, stream>>>(conv_w1, conv_w2, flag, wt);
    k_transw_lin<<<dim3(DH / 32, DIN / 32), bTW, 0, stream>>>(lin1_w, flag, w1t, DIN, DH);
    k_transw_lin<<<dim3(DOUT / 32, DH / 32), bTW, 0, stream>>>(lin2_w, flag, w2t, DH, DOUT);
    k_convx<<<dim3((unsigned)(((size_t)N * DIN + 255) / 256)), blk, 0, stream>>>(x, flag, xb, N * DIN);

    // lin1: x0 = relu(x @ lin1_w + b); also emit sliced copy for layer-0 gather
    gemm_mfma<DH, DIN, 0><<<gB, blk512, 0, stream>>>(xb, w1t, lin1_b, flag, x0, x0s, N);

    const float invTotal = 1.0f / ((float)N * (float)DH);
    for (int l = 0; l < NLAYERS; l++) {
        const short* hsrc = (l == 0) ? x0s : (const short*)h;
        size_t loff = (l == 0) ? 0 : (size_t)(l - 1) * DH;
        const float* st = (l == 0) ? stats : stats + 2 * (l - 1);
        k_gather3<<<gG, blk, 0, stream>>>(rowptr, csr, dis, hsrc, agg,
                                          gam, bet, loff, st, invTotal,
                                          l > 0 ? 1 : 0, flag, N);
        gemm_layer3<<<gB, blk512, 0, stream>>>(agg, x0, wt + (size_t)l * 131072,
                                               h, stats + 2 * l,
                                               (l < NLAYERS - 1) ? 1 : 0, N);
    }
    // final LN + relu in place (row-major h), then lin2
    k_applyT<<<gElem, blk, 0, stream>>>(h, stats + 2 * (NLAYERS - 1), invTotal,
                                        gam, bet, (size_t)(NLAYERS - 1) * DH,
                                        flag, (int)NDH);
    gemm_mfma<DOUT, DH, 1><<<gB, blk512, 0, stream>>>((const short*)h, w2t, lin2_b,
                                                      flag, d_out, nullptr, N);
}